// Round 11
// baseline (211.445 us; speedup 1.0000x reference)
//
#include <hip/hip_runtime.h>

#define N_NODES 100000
#define N_ROWS_PAD 100032   // multiple of 64 for the MFMA kernel
#define N_EDGES 1600000
#define F_IN    128
#define HID     256
#define C_OUT   4

#define NB 391        // ceil(N_NODES/256) buckets
#define EPT 16        // edges per thread in bucket kernels

#define GEMM_BLOCKS 256
#define NTASKS 6252   // N_ROWS_PAD / 16

typedef short short8v __attribute__((ext_vector_type(8)));
typedef unsigned short u16x8 __attribute__((ext_vector_type(8)));
typedef float f32x4 __attribute__((ext_vector_type(4)));

__device__ __forceinline__ ushort f2b(float f) {
    union { float f; unsigned u; } v; v.f = f;
    unsigned u = v.u;
    return (ushort)((u + 0x7FFFu + ((u >> 16) & 1u)) >> 16);   // RNE
}
__device__ __forceinline__ float b2f(ushort u) {
    union { unsigned u; float f; } v; v.u = ((unsigned)u) << 16; return v.f;
}

// async global->LDS, 16B per lane; lds dest = wave-uniform base + lane*16
__device__ __forceinline__ void gload16(const void* g, void* l) {
    __builtin_amdgcn_global_load_lds(
        (const __attribute__((address_space(1))) unsigned int*)g,
        (__attribute__((address_space(3))) unsigned int*)l, 16, 0, 0);
}

// sum-reduce over the 16 lanes of a DPP row via row_ror adds (VALU pipe,
// not the DS pipe -- __shfl_xor would emit ds_swizzle/bpermute and contend
// with the MFMA kernel's ds_read_b128 stream).
template <int CTRL>
__device__ __forceinline__ float dpp_radd(float x) {
    int y = __builtin_amdgcn_update_dpp(0, __float_as_int(x), CTRL, 0xf, 0xf, true);
    return x + __int_as_float(y);
}
__device__ __forceinline__ float row16_sum(float x) {
    x = dpp_radd<0x128>(x);   // row_ror:8
    x = dpp_radd<0x124>(x);   // row_ror:4
    x = dpp_radd<0x122>(x);   // row_ror:2
    x = dpp_radd<0x121>(x);   // row_ror:1
    return x;
}

// ---------------------------------------------------------------------------
// K1: count edges per 256-node BUCKET (LDS hist -> 391 global counters).
__global__ __launch_bounds__(256) void k_bcount(const int* __restrict__ ei,
                                                int* __restrict__ bktcnt) {
    __shared__ int hist[NB];
    int t = threadIdx.x;
    for (int i = t; i < NB; i += 256) hist[i] = 0;
    __syncthreads();
    int base = blockIdx.x * (256 * EPT);
    #pragma unroll
    for (int i = 0; i < EPT; ++i) {
        int e = base + i * 256 + t;
        if (e < N_EDGES) atomicAdd(&hist[ei[N_EDGES + e] >> 8], 1);
    }
    __syncthreads();
    for (int i = t; i < NB; i += 256)
        if (hist[i]) atomicAdd(&bktcnt[i], hist[i]);
}

// K2: scan 391 bucket counts -> boff (bucket CSR offsets) + bcur copy.
__global__ void k_bscan(const int* __restrict__ bktcnt, int* __restrict__ boff,
                        int* __restrict__ bcur) {
    __shared__ int sh[512];
    int t = threadIdx.x;
    int v = (t < NB) ? bktcnt[t] : 0;
    sh[t] = v;
    __syncthreads();
    #pragma unroll
    for (int off = 1; off < 512; off <<= 1) {
        int add = (t >= off) ? sh[t - off] : 0;
        __syncthreads();
        sh[t] += add;
        __syncthreads();
    }
    int excl = sh[t] - v;
    boff[t] = excl;           // boff[NB] = N_EDGES lands naturally at t==NB
    bcur[t] = excl;
}

// K3a: bucket edges by dst>>8; packed entry = src | (dst&255)<<20
// (src < 2^17, so bits don't collide). Halves ebuf traffic vs int2.
__global__ __launch_bounds__(256) void k_bucket(const int* __restrict__ ei,
                                                int* __restrict__ bcur,
                                                int* __restrict__ ebuf) {
    __shared__ int hist[NB];
    __shared__ int sbase[NB];
    int t = threadIdx.x;
    for (int i = t; i < NB; i += 256) hist[i] = 0;
    __syncthreads();
    int pk[EPT], bkt[EPT], lofs[EPT];
    int base = blockIdx.x * (256 * EPT);
    #pragma unroll
    for (int i = 0; i < EPT; ++i) {
        int e = base + i * 256 + t;
        if (e < N_EDGES) {
            int s = ei[e], d = ei[N_EDGES + e];
            pk[i] = s | ((d & 255) << 20);
            bkt[i] = d >> 8;
            lofs[i] = atomicAdd(&hist[bkt[i]], 1);
        } else bkt[i] = -1;
    }
    __syncthreads();
    for (int i = t; i < NB; i += 256) {
        int h = hist[i];
        sbase[i] = h ? atomicAdd(&bcur[i], h) : 0;
    }
    __syncthreads();
    #pragma unroll
    for (int i = 0; i < EPT; ++i) {
        if (bkt[i] >= 0)
            ebuf[sbase[bkt[i]] + lofs[i]] = pk[i];
    }
}

// K3b: one block per bucket; bucket's edges staged in LDS (avg ~4096, cap
// 8192). Pass 1: per-node degree + in-block scan -> rowptr/inv_deg.
// Pass 2: place csr_src via LDS cursors into this bucket's CSR window.
__global__ __launch_bounds__(256) void k_place(const int* __restrict__ boff,
                                               const int* __restrict__ ebuf,
                                               int* __restrict__ rowptr,
                                               float* __restrict__ inv_deg,
                                               int* __restrict__ csr_src) {
    __shared__ int eld[8192];
    __shared__ int ldeg[256];
    __shared__ int sh[256];
    __shared__ int lcur[256];
    int b = blockIdx.x, t = threadIdx.x;
    int e0 = boff[b], e1 = boff[b + 1];
    int cnt = e1 - e0;
    int nc = min(cnt, 8192);
    for (int i = t; i < nc; i += 256) eld[i] = ebuf[e0 + i];
    ldeg[t] = 0;
    __syncthreads();
    for (int i = t; i < cnt; i += 256) {
        int ev = (i < nc) ? eld[i] : ebuf[e0 + i];
        atomicAdd(&ldeg[(ev >> 20) & 255], 1);
    }
    __syncthreads();
    int v = ldeg[t];
    sh[t] = v;
    __syncthreads();
    #pragma unroll
    for (int off = 1; off < 256; off <<= 1) {
        int add = (t >= off) ? sh[t - off] : 0;
        __syncthreads();
        sh[t] += add;
        __syncthreads();
    }
    int start = e0 + sh[t] - v;
    int node = b * 256 + t;
    if (node < N_NODES) {
        rowptr[node] = start;
        inv_deg[node] = (v > 0) ? 1.0f / (float)v : 0.0f;
    }
    if (b == 0 && t == 0) rowptr[N_NODES] = N_EDGES;
    lcur[t] = start;
    __syncthreads();
    for (int i = t; i < cnt; i += 256) {
        int ev = (i < nc) ? eld[i] : ebuf[e0 + i];
        int pos = atomicAdd(&lcur[(ev >> 20) & 255], 1);
        csr_src[pos] = ev & 0xFFFFF;
    }
}

// K_xcast: bf16-cast x into ABF[row][128:256]  (3.2M threads, each 4 floats)
__global__ void k_xcast(const float* __restrict__ x, ushort* __restrict__ abf) {
    int t = blockIdx.x * 256 + threadIdx.x;        // [0, 3.2M)
    float4 xv = *(const float4*)(x + (size_t)t * 4);
    int row = t >> 5;
    int colq = (t & 31) * 4;
    ushort4 o; o.x = f2b(xv.x); o.y = f2b(xv.y); o.z = f2b(xv.z); o.w = f2b(xv.w);
    *(ushort4*)(abf + (size_t)row * 256 + 128 + colq) = o;
}

// K_wbf: WBF[col][k] bf16: [w1_l | w1_r] along k; also pack w2t[col][8]
__global__ void k_wbf(const float* __restrict__ w1l, const float* __restrict__ w1r,
                      const float* __restrict__ w2l, const float* __restrict__ w2r,
                      ushort* __restrict__ wbf, float* __restrict__ w2t) {
    int i = blockIdx.x * 256 + threadIdx.x;        // [0, 65536)
    int col = i >> 8, k = i & 255;
    float v = (k < 128) ? w1l[col * 128 + k] : w1r[col * 128 + (k - 128)];
    wbf[i] = f2b(v);
    if (i < 256) {
        #pragma unroll
        for (int c = 0; c < 4; ++c) {
            w2t[i * 8 + c]     = w2l[c * HID + i];
            w2t[i * 8 + 4 + c] = w2r[c * HID + i];
        }
    }
}

// K4: mean-aggregate bf16 x-rows over in-edges. One wave per node; 16 lanes
// per edge, 4-way unrolled -> 16 row-gathers in flight per wave (round 10
// showed latency-bound: hbm 43%, VALU 49%, occupancy 70%, nothing pegged).
__global__ void k_aggregate(const int* __restrict__ rowptr, const int* __restrict__ csr_src,
                            const float* __restrict__ inv_deg, ushort* __restrict__ abf) {
    int lane = threadIdx.x & 63;
    int v = blockIdx.x * 4 + (threadIdx.x >> 6);
    if (v >= N_NODES) return;
    int r0 = rowptr[v], r1 = rowptr[v + 1];
    int q = lane >> 4, li = lane & 15;
    float a0[8], a1[8], a2[8], a3[8];
    #pragma unroll
    for (int j = 0; j < 8; ++j) { a0[j] = 0.f; a1[j] = 0.f; a2[j] = 0.f; a3[j] = 0.f; }
    int e = r0 + q;
    for (; e + 12 < r1; e += 16) {
        int s0 = csr_src[e];
        int s1 = csr_src[e + 4];
        int s2 = csr_src[e + 8];
        int s3 = csr_src[e + 12];
        u16x8 u0 = *(const u16x8*)(abf + (size_t)s0 * 256 + 128 + li * 8);
        u16x8 u1 = *(const u16x8*)(abf + (size_t)s1 * 256 + 128 + li * 8);
        u16x8 u2 = *(const u16x8*)(abf + (size_t)s2 * 256 + 128 + li * 8);
        u16x8 u3 = *(const u16x8*)(abf + (size_t)s3 * 256 + 128 + li * 8);
        #pragma unroll
        for (int j = 0; j < 8; ++j) {
            a0[j] += b2f(u0[j]); a1[j] += b2f(u1[j]);
            a2[j] += b2f(u2[j]); a3[j] += b2f(u3[j]);
        }
    }
    for (; e < r1; e += 4) {
        int s0 = csr_src[e];
        u16x8 u0 = *(const u16x8*)(abf + (size_t)s0 * 256 + 128 + li * 8);
        #pragma unroll
        for (int j = 0; j < 8; ++j) a0[j] += b2f(u0[j]);
    }
    #pragma unroll
    for (int j = 0; j < 8; ++j) {
        float s = (a0[j] + a1[j]) + (a2[j] + a3[j]);
        s += __shfl_xor(s, 16);
        s += __shfl_xor(s, 32);
        a0[j] = s;
    }
    if (q == 0) {
        float id = inv_deg[v];
        u16x8 o;
        #pragma unroll
        for (int j = 0; j < 8; ++j) o[j] = f2b(a0[j] * id);
        *(u16x8*)(abf + (size_t)v * 256 + li * 8) = o;
    }
}

// K5: persistent MFMA GEMM  h = relu(ABF @ WBF^T + b1)  fused with layer-2
//     projections z = h @ w2l^T, r = h @ w2r^T  (h never materialized).
// 256 blocks x 256 threads (4 waves), 1 block/CU (128KB LDS). FULL B staged
// once; one __syncthreads; each wave owns 16-row tasks. sched_barrier(0)
// fences bound live ranges -> no spill. Epilogue reduce uses DPP row_ror
// adds (VALU) instead of shfl_xor (DS pipe) -- halves DS-pipe ops/task.
__global__ __launch_bounds__(256, 1) void k_mfma(
    const ushort* __restrict__ abf, const ushort* __restrict__ wbf,
    const float* __restrict__ b1, const float* __restrict__ w2t,
    float* __restrict__ zb, float* __restrict__ rb)
{
    __shared__ ushort bufB[16 * 8 * 512];   // 128KB: sub-buffer (n*8+kc) x 1KB

    int t = threadIdx.x;
    int w = t >> 6, l = t & 63;
    int lr = l & 15, lk = l >> 4;

    // stage all of B: wave w stages sub-buffers w*32 .. w*32+31
    #pragma unroll
    for (int j = 0; j < 32; ++j) {
        int sb = w * 32 + j;
        int n = sb >> 3, kc = sb & 7;
        gload16(wbf + (size_t)(n * 16 + lr) * 256 + kc * 32 + lk * 8,
                &bufB[sb * 512]);
    }
    __syncthreads();   // only barrier in the kernel

    int wid = blockIdx.x * 4 + w;                          // [0, 1024)
    int ps = (int)(((unsigned)wid * NTASKS) >> 10);        // balanced /1024
    int pe = (int)(((unsigned)(wid + 1) * NTASKS) >> 10);

    for (int p = ps; p < pe; ++p) {
        size_t r0 = (size_t)p * 16;
        // hoist this task's 8 A-frags (16B contiguous per lane, L3-hot)
        short8v af[8];
        const ushort* a0 = abf + (r0 + lr) * 256 + lk * 8;
        #pragma unroll
        for (int kc = 0; kc < 8; ++kc)
            af[kc] = *(const short8v*)(a0 + kc * 32);
        __builtin_amdgcn_sched_barrier(0);

        f32x4 acc[16] = {};
        #pragma unroll
        for (int kc = 0; kc < 8; ++kc) {
            #pragma unroll
            for (int n = 0; n < 8; ++n) {
                short8v bf = *(const short8v*)&bufB[(n * 8 + kc) * 512 + l * 8];
                acc[n] = __builtin_amdgcn_mfma_f32_16x16x32_bf16(af[kc], bf, acc[n], 0, 0, 0);
            }
            __builtin_amdgcn_sched_barrier(0);
            #pragma unroll
            for (int n = 8; n < 16; ++n) {
                short8v bf = *(const short8v*)&bufB[(n * 8 + kc) * 512 + l * 8];
                acc[n] = __builtin_amdgcn_mfma_f32_16x16x32_bf16(af[kc], bf, acc[n], 0, 0, 0);
            }
            __builtin_amdgcn_sched_barrier(0);
        }

        // epilogue: bias+relu, layer-2 partials over this lane's 16 cols,
        // DPP row-rotate sum over the 16 lr-lanes, write z,r.
        float pz[4][8];
        #pragma unroll
        for (int q = 0; q < 4; ++q)
            #pragma unroll
            for (int c = 0; c < 8; ++c) pz[q][c] = 0.f;
        #pragma unroll
        for (int n = 0; n < 16; ++n) {
            int col = n * 16 + lr;
            float bias = b1[col];
            f32x4 wa = *(const f32x4*)(w2t + col * 8);
            f32x4 wb = *(const f32x4*)(w2t + col * 8 + 4);
            #pragma unroll
            for (int q = 0; q < 4; ++q) {
                float h = fmaxf(acc[n][q] + bias, 0.f);
                pz[q][0] += h * wa[0]; pz[q][1] += h * wa[1];
                pz[q][2] += h * wa[2]; pz[q][3] += h * wa[3];
                pz[q][4] += h * wb[0]; pz[q][5] += h * wb[1];
                pz[q][6] += h * wb[2]; pz[q][7] += h * wb[3];
            }
        }
        __builtin_amdgcn_sched_barrier(0);
        #pragma unroll
        for (int q = 0; q < 4; ++q)
            #pragma unroll
            for (int c = 0; c < 8; ++c)
                pz[q][c] = row16_sum(pz[q][c]);
        if (lr == 0) {
            #pragma unroll
            for (int q = 0; q < 4; ++q) {
                size_t row = r0 + lk * 4 + q;   // C/D row=(l>>4)*4+reg
                if (row < N_NODES) {
                    *(float4*)(zb + row * 4) = make_float4(pz[q][0], pz[q][1], pz[q][2], pz[q][3]);
                    *(float4*)(rb + row * 4) = make_float4(pz[q][4], pz[q][5], pz[q][6], pz[q][7]);
                }
            }
        }
    }
}

// K6: aggregate z over in-edges, add bias + root term, log_softmax, write out.
__global__ void k_final(const float* __restrict__ zb, const float* __restrict__ rb,
                        const int* __restrict__ rowptr, const int* __restrict__ csr_src,
                        const float* __restrict__ inv_deg, const float* __restrict__ b2,
                        float* __restrict__ out) {
    int lane = threadIdx.x & 63;
    int v = blockIdx.x * 4 + (threadIdx.x >> 6);
    if (v >= N_NODES) return;
    int r0 = rowptr[v], r1 = rowptr[v + 1];
    float a0 = 0.f, a1 = 0.f, a2 = 0.f, a3 = 0.f;
    for (int idx = r0 + lane; idx < r1; idx += 64) {
        int s = csr_src[idx];
        float4 zv = *(const float4*)(zb + (size_t)s * 4);
        a0 += zv.x; a1 += zv.y; a2 += zv.z; a3 += zv.w;
    }
    #pragma unroll
    for (int off = 1; off < 64; off <<= 1) {
        a0 += __shfl_xor(a0, off);
        a1 += __shfl_xor(a1, off);
        a2 += __shfl_xor(a2, off);
        a3 += __shfl_xor(a3, off);
    }
    if (lane == 0) {
        float id = inv_deg[v];
        float4 rv = *(const float4*)(rb + (size_t)v * 4);
        float4 b2v = *(const float4*)b2;
        float h0 = a0 * id + b2v.x + rv.x;
        float h1 = a1 * id + b2v.y + rv.y;
        float h2 = a2 * id + b2v.z + rv.z;
        float h3 = a3 * id + b2v.w + rv.w;
        float mx = fmaxf(fmaxf(h0, h1), fmaxf(h2, h3));
        float s = expf(h0 - mx) + expf(h1 - mx) + expf(h2 - mx) + expf(h3 - mx);
        float lse = mx + logf(s);
        *(float4*)(out + (size_t)v * 4) = make_float4(h0 - lse, h1 - lse, h2 - lse, h3 - lse);
    }
}

// ---------------------------------------------------------------------------
extern "C" void kernel_launch(void* const* d_in, const int* in_sizes, int n_in,
                              void* d_out, int out_size, void* d_ws, size_t ws_size,
                              hipStream_t stream) {
    const float* x   = (const float*)d_in[0];
    const int*   ei  = (const int*)d_in[1];
    const float* w1l = (const float*)d_in[2];
    const float* w1r = (const float*)d_in[3];
    const float* b1  = (const float*)d_in[4];
    const float* w2l = (const float*)d_in[5];
    const float* w2r = (const float*)d_in[6];
    const float* b2  = (const float*)d_in[7];
    float* out = (float*)d_out;

    char* ws = (char*)d_ws;
    size_t off = 0;
    auto alloc = [&](size_t bytes) -> void* {
        void* p = ws + off;
        off = (off + bytes + 255) & ~(size_t)255;
        return p;
    };
    int* bktcnt  = (int*)alloc(512 * 4);
    int* boff    = (int*)alloc(512 * 4);
    int* bcur    = (int*)alloc(512 * 4);
    int* rowptr  = (int*)alloc((N_NODES + 1) * 4);
    int* csr_src = (int*)alloc((size_t)N_EDGES * 4);
    int* ebuf    = (int*)alloc((size_t)N_EDGES * 4);
    float* inv_deg = (float*)alloc(N_NODES * 4);
    ushort* abf  = (ushort*)alloc((size_t)N_ROWS_PAD * 256 * 2);  // [agg | x] bf16
    ushort* wbf  = (ushort*)alloc((size_t)256 * 256 * 2);         // [w1l | w1r] bf16
    float* w2t   = (float*)alloc(256 * 8 * 4);                    // [col][z0..3 r0..3]
    float* zb    = (float*)alloc((size_t)N_NODES * 4 * 4);
    float* rb    = (float*)alloc((size_t)N_NODES * 4 * 4);

    hipMemsetAsync(bktcnt, 0, 512 * 4, stream);

    const int BKB = (N_EDGES + 256 * EPT - 1) / (256 * EPT);   // 391
    k_bcount<<<BKB, 256, 0, stream>>>(ei, bktcnt);
    k_bscan<<<1, 512, 0, stream>>>(bktcnt, boff, bcur);
    k_bucket<<<BKB, 256, 0, stream>>>(ei, bcur, ebuf);
    k_place<<<NB, 256, 0, stream>>>(boff, ebuf, rowptr, inv_deg, csr_src);
    k_wbf<<<256, 256, 0, stream>>>(w1l, w1r, w2l, w2r, wbf, w2t);
    k_xcast<<<12500, 256, 0, stream>>>(x, abf);
    k_aggregate<<<(N_NODES + 3) / 4, 256, 0, stream>>>(rowptr, csr_src, inv_deg, abf);
    k_mfma<<<GEMM_BLOCKS, 256, 0, stream>>>(abf, wbf, b1, w2t, zb, rb);
    k_final<<<(N_NODES + 3) / 4, 256, 0, stream>>>(zb, rb, rowptr, csr_src, inv_deg, b2, out);
}

// Round 12
// 188.570 us; speedup vs baseline: 1.1213x; 1.1213x over previous
//
#include <hip/hip_runtime.h>

#define N_NODES 100000
#define N_ROWS_PAD 100032   // multiple of 64 for the MFMA kernel
#define N_EDGES 1600000
#define F_IN    128
#define HID     256
#define C_OUT   4

#define NB 391        // ceil(N_NODES/256) buckets
#define EPT 16        // edges per thread in bucket kernels
#define SLACK 8192    // per-bucket ebuf capacity (avg fill ~4092)

#define GEMM_BLOCKS 256
#define NTASKS 6252   // N_ROWS_PAD / 16

typedef short short8v __attribute__((ext_vector_type(8)));
typedef unsigned short u16x8 __attribute__((ext_vector_type(8)));
typedef float f32x4 __attribute__((ext_vector_type(4)));

__device__ __forceinline__ ushort f2b(float f) {
    union { float f; unsigned u; } v; v.f = f;
    unsigned u = v.u;
    return (ushort)((u + 0x7FFFu + ((u >> 16) & 1u)) >> 16);   // RNE
}
__device__ __forceinline__ float b2f(ushort u) {
    union { unsigned u; float f; } v; v.u = ((unsigned)u) << 16; return v.f;
}

// async global->LDS, 16B per lane; lds dest = wave-uniform base + lane*16
__device__ __forceinline__ void gload16(const void* g, void* l) {
    __builtin_amdgcn_global_load_lds(
        (const __attribute__((address_space(1))) unsigned int*)g,
        (__attribute__((address_space(3))) unsigned int*)l, 16, 0, 0);
}

// sum-reduce over the 16 lanes of a DPP row via row_ror adds (VALU pipe, not
// the DS pipe -- shfl_xor would contend with ds_read_b128 in k_mfma).
template <int CTRL>
__device__ __forceinline__ float dpp_radd(float x) {
    int y = __builtin_amdgcn_update_dpp(0, __float_as_int(x), CTRL, 0xf, 0xf, true);
    return x + __int_as_float(y);
}
__device__ __forceinline__ float row16_sum(float x) {
    x = dpp_radd<0x128>(x);   // row_ror:8
    x = dpp_radd<0x124>(x);   // row_ror:4
    x = dpp_radd<0x122>(x);   // row_ror:2
    x = dpp_radd<0x121>(x);   // row_ror:1
    return x;
}

// ---------------------------------------------------------------------------
// K0: init bucket cursors to slack-region bases (replaces k_bcount+memset:
// slack regions need no pre-counting pass).
__global__ void k_binit(int* __restrict__ bcur) {
    int t = blockIdx.x * 256 + threadIdx.x;
    if (t < 512) bcur[t] = t * SLACK;
}

// K1: bucket edges by dst>>8 into per-bucket SLACK regions; packed entry =
// src | (dst&255)<<20 (src < 2^17). LDS hist -> one global atomic per
// (block,bucket) reserves a contiguous run -> clustered writes.
__global__ __launch_bounds__(256) void k_bucket(const int* __restrict__ ei,
                                                int* __restrict__ bcur,
                                                int* __restrict__ ebuf) {
    __shared__ int hist[NB];
    __shared__ int sbase[NB];
    int t = threadIdx.x;
    for (int i = t; i < NB; i += 256) hist[i] = 0;
    __syncthreads();
    int pk[EPT], bkt[EPT], lofs[EPT];
    int base = blockIdx.x * (256 * EPT);
    #pragma unroll
    for (int i = 0; i < EPT; ++i) {
        int e = base + i * 256 + t;
        if (e < N_EDGES) {
            int s = ei[e], d = ei[N_EDGES + e];
            pk[i] = s | ((d & 255) << 20);
            bkt[i] = d >> 8;
            lofs[i] = atomicAdd(&hist[bkt[i]], 1);
        } else bkt[i] = -1;
    }
    __syncthreads();
    for (int i = t; i < NB; i += 256) {
        int h = hist[i];
        sbase[i] = h ? atomicAdd(&bcur[i], h) : 0;
    }
    __syncthreads();
    #pragma unroll
    for (int i = 0; i < EPT; ++i) {
        if (bkt[i] >= 0)
            ebuf[sbase[bkt[i]] + lofs[i]] = pk[i];
    }
}

// K2: derive exact bucket counts from final cursors, scan -> boff.
__global__ void k_bscan(const int* __restrict__ bcur, int* __restrict__ boff) {
    __shared__ int sh[512];
    int t = threadIdx.x;
    int v = (t < NB) ? (bcur[t] - t * SLACK) : 0;
    sh[t] = v;
    __syncthreads();
    #pragma unroll
    for (int off = 1; off < 512; off <<= 1) {
        int add = (t >= off) ? sh[t - off] : 0;
        __syncthreads();
        sh[t] += add;
        __syncthreads();
    }
    boff[t] = sh[t] - v;      // boff[NB] = N_EDGES lands at t==NB
}

// K3: one block per bucket; stage bucket's edges from its slack region into
// LDS. Pass 1: per-node degree + in-block scan -> rowptr/inv_deg (no global
// atomics). Pass 2: compact to exact CSR via LDS cursors.
__global__ __launch_bounds__(256) void k_place(const int* __restrict__ boff,
                                               const int* __restrict__ ebuf,
                                               int* __restrict__ rowptr,
                                               float* __restrict__ inv_deg,
                                               int* __restrict__ csr_src) {
    __shared__ int eld[SLACK];
    __shared__ int ldeg[256];
    __shared__ int sh[256];
    __shared__ int lcur[256];
    int b = blockIdx.x, t = threadIdx.x;
    int e0 = boff[b];
    int cnt = boff[b + 1] - e0;
    const int* src = ebuf + (size_t)b * SLACK;
    for (int i = t; i < cnt; i += 256) eld[i] = src[i];
    ldeg[t] = 0;
    __syncthreads();
    for (int i = t; i < cnt; i += 256)
        atomicAdd(&ldeg[(eld[i] >> 20) & 255], 1);
    __syncthreads();
    int v = ldeg[t];
    sh[t] = v;
    __syncthreads();
    #pragma unroll
    for (int off = 1; off < 256; off <<= 1) {
        int add = (t >= off) ? sh[t - off] : 0;
        __syncthreads();
        sh[t] += add;
        __syncthreads();
    }
    int start = e0 + sh[t] - v;
    int node = b * 256 + t;
    if (node < N_NODES) {
        rowptr[node] = start;
        inv_deg[node] = (v > 0) ? 1.0f / (float)v : 0.0f;
    }
    if (b == 0 && t == 0) rowptr[N_NODES] = N_EDGES;
    lcur[t] = start;
    __syncthreads();
    for (int i = t; i < cnt; i += 256) {
        int ev = eld[i];
        int pos = atomicAdd(&lcur[(ev >> 20) & 255], 1);
        csr_src[pos] = ev & 0xFFFFF;
    }
}

// K_xcast: bf16-cast x into ABF[row][128:256]  (3.2M threads, each 4 floats)
__global__ void k_xcast(const float* __restrict__ x, ushort* __restrict__ abf) {
    int t = blockIdx.x * 256 + threadIdx.x;        // [0, 3.2M)
    float4 xv = *(const float4*)(x + (size_t)t * 4);
    int row = t >> 5;
    int colq = (t & 31) * 4;
    ushort4 o; o.x = f2b(xv.x); o.y = f2b(xv.y); o.z = f2b(xv.z); o.w = f2b(xv.w);
    *(ushort4*)(abf + (size_t)row * 256 + 128 + colq) = o;
}

// K_wbf: WBF[col][k] bf16: [w1_l | w1_r] along k; also pack w2t[col][8]
__global__ void k_wbf(const float* __restrict__ w1l, const float* __restrict__ w1r,
                      const float* __restrict__ w2l, const float* __restrict__ w2r,
                      ushort* __restrict__ wbf, float* __restrict__ w2t) {
    int i = blockIdx.x * 256 + threadIdx.x;        // [0, 65536)
    int col = i >> 8, k = i & 255;
    float v = (k < 128) ? w1l[col * 128 + k] : w1r[col * 128 + (k - 128)];
    wbf[i] = f2b(v);
    if (i < 256) {
        #pragma unroll
        for (int c = 0; c < 4; ++c) {
            w2t[i * 8 + c]     = w2l[c * HID + i];
            w2t[i * 8 + 4 + c] = w2r[c * HID + i];
        }
    }
}

// K4: mean-aggregate bf16 x-rows over in-edges. One wave per node; 16 lanes
// per edge, 2-way unrolled (8 gathers in flight). Round-11's 4-way unroll
// REGRESSED (61->72us, occupancy 70->51%): the gather stream is near its
// random-access bandwidth ceiling (~3.4 TB/s), not latency-starved.
__global__ void k_aggregate(const int* __restrict__ rowptr, const int* __restrict__ csr_src,
                            const float* __restrict__ inv_deg, ushort* __restrict__ abf) {
    int lane = threadIdx.x & 63;
    int v = blockIdx.x * 4 + (threadIdx.x >> 6);
    if (v >= N_NODES) return;
    int r0 = rowptr[v], r1 = rowptr[v + 1];
    int q = lane >> 4, li = lane & 15;
    float a0[8], a1[8];
    #pragma unroll
    for (int j = 0; j < 8; ++j) { a0[j] = 0.f; a1[j] = 0.f; }
    int e = r0 + q;
    for (; e + 4 < r1; e += 8) {
        int s0 = csr_src[e];
        int s1 = csr_src[e + 4];
        u16x8 u0 = *(const u16x8*)(abf + (size_t)s0 * 256 + 128 + li * 8);
        u16x8 u1 = *(const u16x8*)(abf + (size_t)s1 * 256 + 128 + li * 8);
        #pragma unroll
        for (int j = 0; j < 8; ++j) { a0[j] += b2f(u0[j]); a1[j] += b2f(u1[j]); }
    }
    if (e < r1) {
        int s0 = csr_src[e];
        u16x8 u0 = *(const u16x8*)(abf + (size_t)s0 * 256 + 128 + li * 8);
        #pragma unroll
        for (int j = 0; j < 8; ++j) a0[j] += b2f(u0[j]);
    }
    #pragma unroll
    for (int j = 0; j < 8; ++j) {
        float s = a0[j] + a1[j];
        s += __shfl_xor(s, 16);
        s += __shfl_xor(s, 32);
        a0[j] = s;
    }
    if (q == 0) {
        float id = inv_deg[v];
        u16x8 o;
        #pragma unroll
        for (int j = 0; j < 8; ++j) o[j] = f2b(a0[j] * id);
        *(u16x8*)(abf + (size_t)v * 256 + li * 8) = o;
    }
}

// K5: persistent MFMA GEMM  h = relu(ABF @ WBF^T + b1)  fused with layer-2
//     projections z = h @ w2l^T, r = h @ w2r^T  (h never materialized).
// 256 blocks x 256 threads (4 waves), 1 block/CU (128KB LDS). FULL B staged
// once; one __syncthreads; each wave owns 16-row tasks. sched_barrier(0)
// fences bound live ranges -> no spill. DPP row_ror epilogue reduce (VALU).
__global__ __launch_bounds__(256, 1) void k_mfma(
    const ushort* __restrict__ abf, const ushort* __restrict__ wbf,
    const float* __restrict__ b1, const float* __restrict__ w2t,
    float* __restrict__ zb, float* __restrict__ rb)
{
    __shared__ ushort bufB[16 * 8 * 512];   // 128KB: sub-buffer (n*8+kc) x 1KB

    int t = threadIdx.x;
    int w = t >> 6, l = t & 63;
    int lr = l & 15, lk = l >> 4;

    // stage all of B: wave w stages sub-buffers w*32 .. w*32+31
    #pragma unroll
    for (int j = 0; j < 32; ++j) {
        int sb = w * 32 + j;
        int n = sb >> 3, kc = sb & 7;
        gload16(wbf + (size_t)(n * 16 + lr) * 256 + kc * 32 + lk * 8,
                &bufB[sb * 512]);
    }
    __syncthreads();   // only barrier in the kernel

    int wid = blockIdx.x * 4 + w;                          // [0, 1024)
    int ps = (int)(((unsigned)wid * NTASKS) >> 10);        // balanced /1024
    int pe = (int)(((unsigned)(wid + 1) * NTASKS) >> 10);

    for (int p = ps; p < pe; ++p) {
        size_t r0 = (size_t)p * 16;
        short8v af[8];
        const ushort* a0 = abf + (r0 + lr) * 256 + lk * 8;
        #pragma unroll
        for (int kc = 0; kc < 8; ++kc)
            af[kc] = *(const short8v*)(a0 + kc * 32);
        __builtin_amdgcn_sched_barrier(0);

        f32x4 acc[16] = {};
        #pragma unroll
        for (int kc = 0; kc < 8; ++kc) {
            #pragma unroll
            for (int n = 0; n < 8; ++n) {
                short8v bf = *(const short8v*)&bufB[(n * 8 + kc) * 512 + l * 8];
                acc[n] = __builtin_amdgcn_mfma_f32_16x16x32_bf16(af[kc], bf, acc[n], 0, 0, 0);
            }
            __builtin_amdgcn_sched_barrier(0);
            #pragma unroll
            for (int n = 8; n < 16; ++n) {
                short8v bf = *(const short8v*)&bufB[(n * 8 + kc) * 512 + l * 8];
                acc[n] = __builtin_amdgcn_mfma_f32_16x16x32_bf16(af[kc], bf, acc[n], 0, 0, 0);
            }
            __builtin_amdgcn_sched_barrier(0);
        }

        float pz[4][8];
        #pragma unroll
        for (int q = 0; q < 4; ++q)
            #pragma unroll
            for (int c = 0; c < 8; ++c) pz[q][c] = 0.f;
        #pragma unroll
        for (int n = 0; n < 16; ++n) {
            int col = n * 16 + lr;
            float bias = b1[col];
            f32x4 wa = *(const f32x4*)(w2t + col * 8);
            f32x4 wb = *(const f32x4*)(w2t + col * 8 + 4);
            #pragma unroll
            for (int q = 0; q < 4; ++q) {
                float h = fmaxf(acc[n][q] + bias, 0.f);
                pz[q][0] += h * wa[0]; pz[q][1] += h * wa[1];
                pz[q][2] += h * wa[2]; pz[q][3] += h * wa[3];
                pz[q][4] += h * wb[0]; pz[q][5] += h * wb[1];
                pz[q][6] += h * wb[2]; pz[q][7] += h * wb[3];
            }
        }
        __builtin_amdgcn_sched_barrier(0);
        #pragma unroll
        for (int q = 0; q < 4; ++q)
            #pragma unroll
            for (int c = 0; c < 8; ++c)
                pz[q][c] = row16_sum(pz[q][c]);
        if (lr == 0) {
            #pragma unroll
            for (int q = 0; q < 4; ++q) {
                size_t row = r0 + lk * 4 + q;   // C/D row=(l>>4)*4+reg
                if (row < N_NODES) {
                    *(float4*)(zb + row * 4) = make_float4(pz[q][0], pz[q][1], pz[q][2], pz[q][3]);
                    *(float4*)(rb + row * 4) = make_float4(pz[q][4], pz[q][5], pz[q][6], pz[q][7]);
                }
            }
        }
    }
}

// K6: aggregate z over in-edges, add bias + root term, log_softmax, write out.
__global__ void k_final(const float* __restrict__ zb, const float* __restrict__ rb,
                        const int* __restrict__ rowptr, const int* __restrict__ csr_src,
                        const float* __restrict__ inv_deg, const float* __restrict__ b2,
                        float* __restrict__ out) {
    int lane = threadIdx.x & 63;
    int v = blockIdx.x * 4 + (threadIdx.x >> 6);
    if (v >= N_NODES) return;
    int r0 = rowptr[v], r1 = rowptr[v + 1];
    float a0 = 0.f, a1 = 0.f, a2 = 0.f, a3 = 0.f;
    for (int idx = r0 + lane; idx < r1; idx += 64) {
        int s = csr_src[idx];
        float4 zv = *(const float4*)(zb + (size_t)s * 4);
        a0 += zv.x; a1 += zv.y; a2 += zv.z; a3 += zv.w;
    }
    #pragma unroll
    for (int off = 1; off < 64; off <<= 1) {
        a0 += __shfl_xor(a0, off);
        a1 += __shfl_xor(a1, off);
        a2 += __shfl_xor(a2, off);
        a3 += __shfl_xor(a3, off);
    }
    if (lane == 0) {
        float id = inv_deg[v];
        float4 rv = *(const float4*)(rb + (size_t)v * 4);
        float4 b2v = *(const float4*)b2;
        float h0 = a0 * id + b2v.x + rv.x;
        float h1 = a1 * id + b2v.y + rv.y;
        float h2 = a2 * id + b2v.z + rv.z;
        float h3 = a3 * id + b2v.w + rv.w;
        float mx = fmaxf(fmaxf(h0, h1), fmaxf(h2, h3));
        float s = expf(h0 - mx) + expf(h1 - mx) + expf(h2 - mx) + expf(h3 - mx);
        float lse = mx + logf(s);
        *(float4*)(out + (size_t)v * 4) = make_float4(h0 - lse, h1 - lse, h2 - lse, h3 - lse);
    }
}

// ---------------------------------------------------------------------------
extern "C" void kernel_launch(void* const* d_in, const int* in_sizes, int n_in,
                              void* d_out, int out_size, void* d_ws, size_t ws_size,
                              hipStream_t stream) {
    const float* x   = (const float*)d_in[0];
    const int*   ei  = (const int*)d_in[1];
    const float* w1l = (const float*)d_in[2];
    const float* w1r = (const float*)d_in[3];
    const float* b1  = (const float*)d_in[4];
    const float* w2l = (const float*)d_in[5];
    const float* w2r = (const float*)d_in[6];
    const float* b2  = (const float*)d_in[7];
    float* out = (float*)d_out;

    char* ws = (char*)d_ws;
    size_t off = 0;
    auto alloc = [&](size_t bytes) -> void* {
        void* p = ws + off;
        off = (off + bytes + 255) & ~(size_t)255;
        return p;
    };
    int* bcur    = (int*)alloc(512 * 4);
    int* boff    = (int*)alloc(512 * 4);
    int* rowptr  = (int*)alloc((N_NODES + 1) * 4);
    int* csr_src = (int*)alloc((size_t)N_EDGES * 4);
    int* ebuf    = (int*)alloc((size_t)NB * SLACK * 4);           // 12.8 MB slack
    float* inv_deg = (float*)alloc(N_NODES * 4);
    ushort* abf  = (ushort*)alloc((size_t)N_ROWS_PAD * 256 * 2);  // [agg | x] bf16
    ushort* wbf  = (ushort*)alloc((size_t)256 * 256 * 2);         // [w1l | w1r] bf16
    float* w2t   = (float*)alloc(256 * 8 * 4);                    // [col][z0..3 r0..3]
    float* zb    = (float*)alloc((size_t)N_NODES * 4 * 4);
    float* rb    = (float*)alloc((size_t)N_NODES * 4 * 4);

    const int BKB = (N_EDGES + 256 * EPT - 1) / (256 * EPT);   // 391
    k_binit<<<2, 256, 0, stream>>>(bcur);
    k_bucket<<<BKB, 256, 0, stream>>>(ei, bcur, ebuf);
    k_bscan<<<1, 512, 0, stream>>>(bcur, boff);
    k_place<<<NB, 256, 0, stream>>>(boff, ebuf, rowptr, inv_deg, csr_src);
    k_wbf<<<256, 256, 0, stream>>>(w1l, w1r, w2l, w2r, wbf, w2t);
    k_xcast<<<12500, 256, 0, stream>>>(x, abf);
    k_aggregate<<<(N_NODES + 3) / 4, 256, 0, stream>>>(rowptr, csr_src, inv_deg, abf);
    k_mfma<<<GEMM_BLOCKS, 256, 0, stream>>>(abf, wbf, b1, w2t, zb, rb);
    k_final<<<(N_NODES + 3) / 4, 256, 0, stream>>>(zb, rb, rowptr, csr_src, inv_deg, b2, out);
}

// Round 13
// 183.029 us; speedup vs baseline: 1.1553x; 1.0303x over previous
//
#include <hip/hip_runtime.h>

#define N_NODES 100000
#define N_ROWS_PAD 100032   // multiple of 64 for the MFMA kernel
#define N_EDGES 1600000
#define F_IN    128
#define HID     256
#define C_OUT   4

#define NB 391        // ceil(N_NODES/256) buckets
#define EPT 16        // edges per thread in bucket kernels
#define SLACK 8192    // per-bucket ebuf capacity (avg fill ~4092)
#define BKB 391       // bucket blocks in k_front
#define XCB 12500     // xcast blocks in k_front

#define GEMM_BLOCKS 256
#define NPAIRS 3126   // N_ROWS_PAD / 32 (32-row paired tasks)

typedef short short8v __attribute__((ext_vector_type(8)));
typedef unsigned short u16x8 __attribute__((ext_vector_type(8)));
typedef float f32x4 __attribute__((ext_vector_type(4)));

__device__ __forceinline__ ushort f2b(float f) {
    union { float f; unsigned u; } v; v.f = f;
    unsigned u = v.u;
    return (ushort)((u + 0x7FFFu + ((u >> 16) & 1u)) >> 16);   // RNE
}
__device__ __forceinline__ float b2f(ushort u) {
    union { unsigned u; float f; } v; v.u = ((unsigned)u) << 16; return v.f;
}

// async global->LDS, 16B per lane; lds dest = wave-uniform base + lane*16
__device__ __forceinline__ void gload16(const void* g, void* l) {
    __builtin_amdgcn_global_load_lds(
        (const __attribute__((address_space(1))) unsigned int*)g,
        (__attribute__((address_space(3))) unsigned int*)l, 16, 0, 0);
}

// sum-reduce over the 16 lanes of a DPP row via row_ror adds (VALU pipe, not
// the DS pipe -- shfl_xor would contend with ds_read_b128 in k_mfma).
template <int CTRL>
__device__ __forceinline__ float dpp_radd(float x) {
    int y = __builtin_amdgcn_update_dpp(0, __float_as_int(x), CTRL, 0xf, 0xf, true);
    return x + __int_as_float(y);
}
__device__ __forceinline__ float row16_sum(float x) {
    x = dpp_radd<0x128>(x);   // row_ror:8
    x = dpp_radd<0x124>(x);   // row_ror:4
    x = dpp_radd<0x122>(x);   // row_ror:2
    x = dpp_radd<0x121>(x);   // row_ror:1
    return x;
}

// ---------------------------------------------------------------------------
// K0: init bucket cursors to slack-region bases.
__global__ void k_binit(int* __restrict__ bcur) {
    int t = blockIdx.x * 256 + threadIdx.x;
    if (t < 512) bcur[t] = t * SLACK;
}

// K1 "front": three INDEPENDENT jobs fused into one launch so the
// latency-bound bucket atomics overlap the BW-bound x-cast across CUs
// (the single stream otherwise serializes them):
//   blocks [0,BKB):            bucket edges into slack regions
//   blocks [BKB,BKB+XCB):      bf16-cast x into ABF[row][128:256]
//   blocks [BKB+XCB,+256):     pack WBF (bf16 [w1l|w1r]) and w2t
__global__ __launch_bounds__(256) void k_front(
    const int* __restrict__ ei, int* __restrict__ bcur, int* __restrict__ ebuf,
    const float* __restrict__ x, ushort* __restrict__ abf,
    const float* __restrict__ w1l, const float* __restrict__ w1r,
    const float* __restrict__ w2l, const float* __restrict__ w2r,
    ushort* __restrict__ wbf, float* __restrict__ w2t)
{
    __shared__ int hist[NB];
    __shared__ int sbase[NB];
    int bx = blockIdx.x;
    int t = threadIdx.x;
    if (bx < BKB) {
        // --- bucket: packed entry = src | (dst&255)<<20 (src < 2^17) ---
        for (int i = t; i < NB; i += 256) hist[i] = 0;
        __syncthreads();
        int pk[EPT], bkt[EPT], lofs[EPT];
        int base = bx * (256 * EPT);
        #pragma unroll
        for (int i = 0; i < EPT; ++i) {
            int e = base + i * 256 + t;
            if (e < N_EDGES) {
                int s = ei[e], d = ei[N_EDGES + e];
                pk[i] = s | ((d & 255) << 20);
                bkt[i] = d >> 8;
                lofs[i] = atomicAdd(&hist[bkt[i]], 1);
            } else bkt[i] = -1;
        }
        __syncthreads();
        for (int i = t; i < NB; i += 256) {
            int h = hist[i];
            sbase[i] = h ? atomicAdd(&bcur[i], h) : 0;
        }
        __syncthreads();
        #pragma unroll
        for (int i = 0; i < EPT; ++i) {
            if (bkt[i] >= 0)
                ebuf[sbase[bkt[i]] + lofs[i]] = pk[i];
        }
    } else if (bx < BKB + XCB) {
        // --- xcast ---
        int g = (bx - BKB) * 256 + t;          // [0, 3.2M)
        float4 xv = *(const float4*)(x + (size_t)g * 4);
        int row = g >> 5;
        int colq = (g & 31) * 4;
        ushort4 o; o.x = f2b(xv.x); o.y = f2b(xv.y); o.z = f2b(xv.z); o.w = f2b(xv.w);
        *(ushort4*)(abf + (size_t)row * 256 + 128 + colq) = o;
    } else {
        // --- weight pack ---
        int i = (bx - BKB - XCB) * 256 + t;    // [0, 65536)
        int col = i >> 8, k = i & 255;
        float v = (k < 128) ? w1l[col * 128 + k] : w1r[col * 128 + (k - 128)];
        wbf[i] = f2b(v);
        if (i < 256) {
            #pragma unroll
            for (int c = 0; c < 4; ++c) {
                w2t[i * 8 + c]     = w2l[c * HID + i];
                w2t[i * 8 + 4 + c] = w2r[c * HID + i];
            }
        }
    }
}

// K2: derive exact bucket counts from final cursors, scan -> boff.
__global__ void k_bscan(const int* __restrict__ bcur, int* __restrict__ boff) {
    __shared__ int sh[512];
    int t = threadIdx.x;
    int v = (t < NB) ? (bcur[t] - t * SLACK) : 0;
    sh[t] = v;
    __syncthreads();
    #pragma unroll
    for (int off = 1; off < 512; off <<= 1) {
        int add = (t >= off) ? sh[t - off] : 0;
        __syncthreads();
        sh[t] += add;
        __syncthreads();
    }
    boff[t] = sh[t] - v;      // boff[NB] = N_EDGES lands at t==NB
}

// K3: one block per bucket; stage bucket's edges from its slack region into
// LDS. Pass 1: per-node degree + in-block scan -> rowptr/inv_deg (no global
// atomics). Pass 2: compact to exact CSR via LDS cursors.
__global__ __launch_bounds__(256) void k_place(const int* __restrict__ boff,
                                               const int* __restrict__ ebuf,
                                               int* __restrict__ rowptr,
                                               float* __restrict__ inv_deg,
                                               int* __restrict__ csr_src) {
    __shared__ int eld[SLACK];
    __shared__ int ldeg[256];
    __shared__ int sh[256];
    __shared__ int lcur[256];
    int b = blockIdx.x, t = threadIdx.x;
    int e0 = boff[b];
    int cnt = boff[b + 1] - e0;
    const int* src = ebuf + (size_t)b * SLACK;
    for (int i = t; i < cnt; i += 256) eld[i] = src[i];
    ldeg[t] = 0;
    __syncthreads();
    for (int i = t; i < cnt; i += 256)
        atomicAdd(&ldeg[(eld[i] >> 20) & 255], 1);
    __syncthreads();
    int v = ldeg[t];
    sh[t] = v;
    __syncthreads();
    #pragma unroll
    for (int off = 1; off < 256; off <<= 1) {
        int add = (t >= off) ? sh[t - off] : 0;
        __syncthreads();
        sh[t] += add;
        __syncthreads();
    }
    int start = e0 + sh[t] - v;
    int node = b * 256 + t;
    if (node < N_NODES) {
        rowptr[node] = start;
        inv_deg[node] = (v > 0) ? 1.0f / (float)v : 0.0f;
    }
    if (b == 0 && t == 0) rowptr[N_NODES] = N_EDGES;
    lcur[t] = start;
    __syncthreads();
    for (int i = t; i < cnt; i += 256) {
        int ev = eld[i];
        int pos = atomicAdd(&lcur[(ev >> 20) & 255], 1);
        csr_src[pos] = ev & 0xFFFFF;
    }
}

// K4: mean-aggregate bf16 x-rows over in-edges. One wave per node; 16 lanes
// per edge, 2-way unrolled (8 gathers in flight). 4-way unroll regressed
// (r11): the gather stream is at its random-access service ceiling.
__global__ void k_aggregate(const int* __restrict__ rowptr, const int* __restrict__ csr_src,
                            const float* __restrict__ inv_deg, ushort* __restrict__ abf) {
    int lane = threadIdx.x & 63;
    int v = blockIdx.x * 4 + (threadIdx.x >> 6);
    if (v >= N_NODES) return;
    int r0 = rowptr[v], r1 = rowptr[v + 1];
    int q = lane >> 4, li = lane & 15;
    float a0[8], a1[8];
    #pragma unroll
    for (int j = 0; j < 8; ++j) { a0[j] = 0.f; a1[j] = 0.f; }
    int e = r0 + q;
    for (; e + 4 < r1; e += 8) {
        int s0 = csr_src[e];
        int s1 = csr_src[e + 4];
        u16x8 u0 = *(const u16x8*)(abf + (size_t)s0 * 256 + 128 + li * 8);
        u16x8 u1 = *(const u16x8*)(abf + (size_t)s1 * 256 + 128 + li * 8);
        #pragma unroll
        for (int j = 0; j < 8; ++j) { a0[j] += b2f(u0[j]); a1[j] += b2f(u1[j]); }
    }
    if (e < r1) {
        int s0 = csr_src[e];
        u16x8 u0 = *(const u16x8*)(abf + (size_t)s0 * 256 + 128 + li * 8);
        #pragma unroll
        for (int j = 0; j < 8; ++j) a0[j] += b2f(u0[j]);
    }
    #pragma unroll
    for (int j = 0; j < 8; ++j) {
        float s = a0[j] + a1[j];
        s += __shfl_xor(s, 16);
        s += __shfl_xor(s, 32);
        a0[j] = s;
    }
    if (q == 0) {
        float id = inv_deg[v];
        u16x8 o;
        #pragma unroll
        for (int j = 0; j < 8; ++j) o[j] = f2b(a0[j] * id);
        *(u16x8*)(abf + (size_t)v * 256 + li * 8) = o;
    }
}

// K5: persistent MFMA GEMM, 32-ROW PAIRED tasks: each B-fragment read from
// LDS feeds TWO row-groups (acc0,acc1) -> LDS-read traffic halved (the
// kernel's bound: ~24 tasks/CU x 128 ds_read_b128 x ~12cyc). Round 5's
// pairing spilled because of the 512-thread 128-VGPR cap; at 256 threads
// (256-VGPR budget, r8) + sched_barrier fences (r9) the ~215-reg live set
// fits. If FETCH explodes next profile, it spilled -> revert.
__global__ __launch_bounds__(256, 1) void k_mfma(
    const ushort* __restrict__ abf, const ushort* __restrict__ wbf,
    const float* __restrict__ b1, const float* __restrict__ w2t,
    float* __restrict__ zb, float* __restrict__ rb)
{
    __shared__ ushort bufB[16 * 8 * 512];   // 128KB: sub-buffer (n*8+kc) x 1KB

    int t = threadIdx.x;
    int w = t >> 6, l = t & 63;
    int lr = l & 15, lk = l >> 4;

    // stage all of B: wave w stages sub-buffers w*32 .. w*32+31
    #pragma unroll
    for (int j = 0; j < 32; ++j) {
        int sb = w * 32 + j;
        int n = sb >> 3, kc = sb & 7;
        gload16(wbf + (size_t)(n * 16 + lr) * 256 + kc * 32 + lk * 8,
                &bufB[sb * 512]);
    }
    __syncthreads();   // only barrier in the kernel

    int wid = blockIdx.x * 4 + w;                          // [0, 1024)
    int ps = (int)(((unsigned)wid * NPAIRS) >> 10);        // balanced /1024
    int pe = (int)(((unsigned)(wid + 1) * NPAIRS) >> 10);

    for (int p = ps; p < pe; ++p) {
        size_t r0 = (size_t)p * 32;
        short8v af0[8], af1[8];
        const ushort* pa0 = abf + (r0 + lr) * 256 + lk * 8;
        const ushort* pa1 = abf + (r0 + 16 + lr) * 256 + lk * 8;
        #pragma unroll
        for (int kc = 0; kc < 8; ++kc) {
            af0[kc] = *(const short8v*)(pa0 + kc * 32);
            af1[kc] = *(const short8v*)(pa1 + kc * 32);
        }
        __builtin_amdgcn_sched_barrier(0);

        f32x4 acc0[16] = {}, acc1[16] = {};
        #pragma unroll
        for (int kc = 0; kc < 8; ++kc) {
            #pragma unroll
            for (int n = 0; n < 8; ++n) {
                short8v bf = *(const short8v*)&bufB[(n * 8 + kc) * 512 + l * 8];
                acc0[n] = __builtin_amdgcn_mfma_f32_16x16x32_bf16(af0[kc], bf, acc0[n], 0, 0, 0);
                acc1[n] = __builtin_amdgcn_mfma_f32_16x16x32_bf16(af1[kc], bf, acc1[n], 0, 0, 0);
            }
            __builtin_amdgcn_sched_barrier(0);
            #pragma unroll
            for (int n = 8; n < 16; ++n) {
                short8v bf = *(const short8v*)&bufB[(n * 8 + kc) * 512 + l * 8];
                acc0[n] = __builtin_amdgcn_mfma_f32_16x16x32_bf16(af0[kc], bf, acc0[n], 0, 0, 0);
                acc1[n] = __builtin_amdgcn_mfma_f32_16x16x32_bf16(af1[kc], bf, acc1[n], 0, 0, 0);
            }
            __builtin_amdgcn_sched_barrier(0);
        }

        // epilogue per row-group: bias+relu, layer-2 partials, DPP reduce.
        #pragma unroll
        for (int g = 0; g < 2; ++g) {
            float pz[4][8];
            #pragma unroll
            for (int q = 0; q < 4; ++q)
                #pragma unroll
                for (int c = 0; c < 8; ++c) pz[q][c] = 0.f;
            #pragma unroll
            for (int n = 0; n < 16; ++n) {
                int col = n * 16 + lr;
                float bias = b1[col];
                f32x4 wa = *(const f32x4*)(w2t + col * 8);
                f32x4 wb = *(const f32x4*)(w2t + col * 8 + 4);
                #pragma unroll
                for (int q = 0; q < 4; ++q) {
                    float aq = g ? acc1[n][q] : acc0[n][q];
                    float h = fmaxf(aq + bias, 0.f);
                    pz[q][0] += h * wa[0]; pz[q][1] += h * wa[1];
                    pz[q][2] += h * wa[2]; pz[q][3] += h * wa[3];
                    pz[q][4] += h * wb[0]; pz[q][5] += h * wb[1];
                    pz[q][6] += h * wb[2]; pz[q][7] += h * wb[3];
                }
            }
            __builtin_amdgcn_sched_barrier(0);
            #pragma unroll
            for (int q = 0; q < 4; ++q)
                #pragma unroll
                for (int c = 0; c < 8; ++c)
                    pz[q][c] = row16_sum(pz[q][c]);
            if (lr == 0) {
                #pragma unroll
                for (int q = 0; q < 4; ++q) {
                    size_t row = r0 + g * 16 + lk * 4 + q;  // C/D row=(l>>4)*4+reg
                    if (row < N_NODES) {
                        *(float4*)(zb + row * 4) = make_float4(pz[q][0], pz[q][1], pz[q][2], pz[q][3]);
                        *(float4*)(rb + row * 4) = make_float4(pz[q][4], pz[q][5], pz[q][6], pz[q][7]);
                    }
                }
            }
        }
    }
}

// K6: aggregate z over in-edges, add bias + root term, log_softmax, write out.
__global__ void k_final(const float* __restrict__ zb, const float* __restrict__ rb,
                        const int* __restrict__ rowptr, const int* __restrict__ csr_src,
                        const float* __restrict__ inv_deg, const float* __restrict__ b2,
                        float* __restrict__ out) {
    int lane = threadIdx.x & 63;
    int v = blockIdx.x * 4 + (threadIdx.x >> 6);
    if (v >= N_NODES) return;
    int r0 = rowptr[v], r1 = rowptr[v + 1];
    float a0 = 0.f, a1 = 0.f, a2 = 0.f, a3 = 0.f;
    for (int idx = r0 + lane; idx < r1; idx += 64) {
        int s = csr_src[idx];
        float4 zv = *(const float4*)(zb + (size_t)s * 4);
        a0 += zv.x; a1 += zv.y; a2 += zv.z; a3 += zv.w;
    }
    #pragma unroll
    for (int off = 1; off < 64; off <<= 1) {
        a0 += __shfl_xor(a0, off);
        a1 += __shfl_xor(a1, off);
        a2 += __shfl_xor(a2, off);
        a3 += __shfl_xor(a3, off);
    }
    if (lane == 0) {
        float id = inv_deg[v];
        float4 rv = *(const float4*)(rb + (size_t)v * 4);
        float4 b2v = *(const float4*)b2;
        float h0 = a0 * id + b2v.x + rv.x;
        float h1 = a1 * id + b2v.y + rv.y;
        float h2 = a2 * id + b2v.z + rv.z;
        float h3 = a3 * id + b2v.w + rv.w;
        float mx = fmaxf(fmaxf(h0, h1), fmaxf(h2, h3));
        float s = expf(h0 - mx) + expf(h1 - mx) + expf(h2 - mx) + expf(h3 - mx);
        float lse = mx + logf(s);
        *(float4*)(out + (size_t)v * 4) = make_float4(h0 - lse, h1 - lse, h2 - lse, h3 - lse);
    }
}

// ---------------------------------------------------------------------------
extern "C" void kernel_launch(void* const* d_in, const int* in_sizes, int n_in,
                              void* d_out, int out_size, void* d_ws, size_t ws_size,
                              hipStream_t stream) {
    const float* x   = (const float*)d_in[0];
    const int*   ei  = (const int*)d_in[1];
    const float* w1l = (const float*)d_in[2];
    const float* w1r = (const float*)d_in[3];
    const float* b1  = (const float*)d_in[4];
    const float* w2l = (const float*)d_in[5];
    const float* w2r = (const float*)d_in[6];
    const float* b2  = (const float*)d_in[7];
    float* out = (float*)d_out;

    char* ws = (char*)d_ws;
    size_t off = 0;
    auto alloc = [&](size_t bytes) -> void* {
        void* p = ws + off;
        off = (off + bytes + 255) & ~(size_t)255;
        return p;
    };
    int* bcur    = (int*)alloc(512 * 4);
    int* boff    = (int*)alloc(512 * 4);
    int* rowptr  = (int*)alloc((N_NODES + 1) * 4);
    int* csr_src = (int*)alloc((size_t)N_EDGES * 4);
    int* ebuf    = (int*)alloc((size_t)NB * SLACK * 4);           // 12.8 MB slack
    float* inv_deg = (float*)alloc(N_NODES * 4);
    ushort* abf  = (ushort*)alloc((size_t)N_ROWS_PAD * 256 * 2);  // [agg | x] bf16
    ushort* wbf  = (ushort*)alloc((size_t)256 * 256 * 2);         // [w1l | w1r] bf16
    float* w2t   = (float*)alloc(256 * 8 * 4);                    // [col][z0..3 r0..3]
    float* zb    = (float*)alloc((size_t)N_NODES * 4 * 4);
    float* rb    = (float*)alloc((size_t)N_NODES * 4 * 4);

    k_binit<<<2, 256, 0, stream>>>(bcur);
    k_front<<<BKB + XCB + 256, 256, 0, stream>>>(ei, bcur, ebuf, x, abf,
                                                 w1l, w1r, w2l, w2r, wbf, w2t);
    k_bscan<<<1, 512, 0, stream>>>(bcur, boff);
    k_place<<<NB, 256, 0, stream>>>(boff, ebuf, rowptr, inv_deg, csr_src);
    k_aggregate<<<(N_NODES + 3) / 4, 256, 0, stream>>>(rowptr, csr_src, inv_deg, abf);
    k_mfma<<<GEMM_BLOCKS, 256, 0, stream>>>(abf, wbf, b1, w2t, zb, rb);
    k_final<<<(N_NODES + 3) / 4, 256, 0, stream>>>(zb, rb, rowptr, csr_src, inv_deg, b2, out);
}

// Round 14
// 163.353 us; speedup vs baseline: 1.2944x; 1.1205x over previous
//
#include <hip/hip_runtime.h>

#define N_NODES 100000
#define N_ROWS_PAD 100032   // multiple of 64 for the MFMA kernel
#define N_EDGES 1600000
#define F_IN    128
#define HID     256
#define C_OUT   4

#define NB 391        // ceil(N_NODES/256) buckets
#define EPT 16        // edges per thread in bucket kernels
#define SLACK 8192    // per-bucket ebuf capacity (avg fill ~4092)
#define BKB 391       // bucket blocks in k_front
#define XCB 12500     // xcast blocks in k_front

#define GEMM_BLOCKS 256
#define NPAIRS 3126   // N_ROWS_PAD / 32 (32-row paired tasks)

typedef short short8v __attribute__((ext_vector_type(8)));
typedef unsigned short u16x8 __attribute__((ext_vector_type(8)));
typedef float f32x4 __attribute__((ext_vector_type(4)));

__device__ __forceinline__ ushort f2b(float f) {
    union { float f; unsigned u; } v; v.f = f;
    unsigned u = v.u;
    return (ushort)((u + 0x7FFFu + ((u >> 16) & 1u)) >> 16);   // RNE
}
__device__ __forceinline__ float b2f(ushort u) {
    union { unsigned u; float f; } v; v.u = ((unsigned)u) << 16; return v.f;
}

// async global->LDS, 16B per lane; lds dest = wave-uniform base + lane*16
__device__ __forceinline__ void gload16(const void* g, void* l) {
    __builtin_amdgcn_global_load_lds(
        (const __attribute__((address_space(1))) unsigned int*)g,
        (__attribute__((address_space(3))) unsigned int*)l, 16, 0, 0);
}

// sum-reduce over the 16 lanes of a DPP row via row_ror adds (VALU pipe, not
// the DS pipe -- shfl_xor would contend with ds_read_b128 in k_mfma).
template <int CTRL>
__device__ __forceinline__ float dpp_radd(float x) {
    int y = __builtin_amdgcn_update_dpp(0, __float_as_int(x), CTRL, 0xf, 0xf, true);
    return x + __int_as_float(y);
}
__device__ __forceinline__ float row16_sum(float x) {
    x = dpp_radd<0x128>(x);   // row_ror:8
    x = dpp_radd<0x124>(x);   // row_ror:4
    x = dpp_radd<0x122>(x);   // row_ror:2
    x = dpp_radd<0x121>(x);   // row_ror:1
    return x;
}

// ---------------------------------------------------------------------------
// K1 "front": three INDEPENDENT jobs fused into one launch so the
// latency-bound bucket atomics overlap the BW-bound x-cast across CUs:
//   blocks [0,BKB):            bucket edges into slack regions
//   blocks [BKB,BKB+XCB):      bf16-cast x into ABF[row][128:256]
//   blocks [BKB+XCB,+256):     pack WBF (bf16 [w1l|w1r]) and w2t
// bcur[] are pure COUNT cursors (memset-0 before launch); slack write addr
// = bkt*SLACK + reserved + local. Exact counts land in bcur for k_place.
__global__ __launch_bounds__(256) void k_front(
    const int* __restrict__ ei, int* __restrict__ bcur, int* __restrict__ ebuf,
    const float* __restrict__ x, ushort* __restrict__ abf,
    const float* __restrict__ w1l, const float* __restrict__ w1r,
    const float* __restrict__ w2l, const float* __restrict__ w2r,
    ushort* __restrict__ wbf, float* __restrict__ w2t)
{
    __shared__ int hist[NB];
    __shared__ int sbase[NB];
    int bx = blockIdx.x;
    int t = threadIdx.x;
    if (bx < BKB) {
        // --- bucket: packed entry = src | (dst&255)<<20 (src < 2^17) ---
        for (int i = t; i < NB; i += 256) hist[i] = 0;
        __syncthreads();
        int pk[EPT], bkt[EPT], lofs[EPT];
        int base = bx * (256 * EPT);
        #pragma unroll
        for (int i = 0; i < EPT; ++i) {
            int e = base + i * 256 + t;
            if (e < N_EDGES) {
                int s = ei[e], d = ei[N_EDGES + e];
                pk[i] = s | ((d & 255) << 20);
                bkt[i] = d >> 8;
                lofs[i] = atomicAdd(&hist[bkt[i]], 1);
            } else bkt[i] = -1;
        }
        __syncthreads();
        for (int i = t; i < NB; i += 256) {
            int h = hist[i];
            sbase[i] = h ? atomicAdd(&bcur[i], h) : 0;
        }
        __syncthreads();
        #pragma unroll
        for (int i = 0; i < EPT; ++i) {
            if (bkt[i] >= 0)
                ebuf[(size_t)bkt[i] * SLACK + sbase[bkt[i]] + lofs[i]] = pk[i];
        }
    } else if (bx < BKB + XCB) {
        // --- xcast ---
        int g = (bx - BKB) * 256 + t;          // [0, 3.2M)
        float4 xv = *(const float4*)(x + (size_t)g * 4);
        int row = g >> 5;
        int colq = (g & 31) * 4;
        ushort4 o; o.x = f2b(xv.x); o.y = f2b(xv.y); o.z = f2b(xv.z); o.w = f2b(xv.w);
        *(ushort4*)(abf + (size_t)row * 256 + 128 + colq) = o;
    } else {
        // --- weight pack ---
        int i = (bx - BKB - XCB) * 256 + t;    // [0, 65536)
        int col = i >> 8, k = i & 255;
        float v = (k < 128) ? w1l[col * 128 + k] : w1r[col * 128 + (k - 128)];
        wbf[i] = f2b(v);
        if (i < 256) {
            #pragma unroll
            for (int c = 0; c < 4; ++c) {
                w2t[i * 8 + c]     = w2l[c * HID + i];
                w2t[i * 8 + 4 + c] = w2r[c * HID + i];
            }
        }
    }
}

// K3: one block per bucket. Computes its own CSR base (reduce of bcur[<b] --
// 391 hot L2 reads; replaces the k_bscan launch). Stage bucket edges in LDS;
// pass 1: per-node degree + in-block scan -> rowptr/inv_deg; pass 2: compact
// to exact CSR via LDS cursors.
__global__ __launch_bounds__(256) void k_place(const int* __restrict__ bcur,
                                               const int* __restrict__ ebuf,
                                               int* __restrict__ rowptr,
                                               float* __restrict__ inv_deg,
                                               int* __restrict__ csr_src) {
    __shared__ int eld[SLACK];
    __shared__ int ldeg[256];
    __shared__ int sh[256];
    __shared__ int lcur[256];
    __shared__ int red[256];
    int b = blockIdx.x, t = threadIdx.x;
    int cnt = bcur[b];
    const int* src = ebuf + (size_t)b * SLACK;
    for (int i = t; i < cnt; i += 256) eld[i] = src[i];
    ldeg[t] = 0;
    int part = 0;
    for (int i = t; i < b; i += 256) part += bcur[i];
    red[t] = part;
    __syncthreads();
    #pragma unroll
    for (int s = 128; s > 0; s >>= 1) {
        if (t < s) red[t] += red[t + s];
        __syncthreads();
    }
    int e0 = red[0];
    for (int i = t; i < cnt; i += 256)
        atomicAdd(&ldeg[(eld[i] >> 20) & 255], 1);
    __syncthreads();
    int v = ldeg[t];
    sh[t] = v;
    __syncthreads();
    #pragma unroll
    for (int off = 1; off < 256; off <<= 1) {
        int add = (t >= off) ? sh[t - off] : 0;
        __syncthreads();
        sh[t] += add;
        __syncthreads();
    }
    int start = e0 + sh[t] - v;
    int node = b * 256 + t;
    if (node < N_NODES) {
        rowptr[node] = start;
        inv_deg[node] = (v > 0) ? 1.0f / (float)v : 0.0f;
    }
    if (b == 0 && t == 0) rowptr[N_NODES] = N_EDGES;
    lcur[t] = start;
    __syncthreads();
    for (int i = t; i < cnt; i += 256) {
        int ev = eld[i];
        int pos = atomicAdd(&lcur[(ev >> 20) & 255], 1);
        csr_src[pos] = ev & 0xFFFFF;
    }
}

// K4: mean-aggregate bf16 x-rows over in-edges. One wave per node; 16 lanes
// per edge, 2-way unrolled (8 gathers in flight). 4-way unroll regressed
// (r11): the gather stream is at its random-access service ceiling.
__global__ void k_aggregate(const int* __restrict__ rowptr, const int* __restrict__ csr_src,
                            const float* __restrict__ inv_deg, ushort* __restrict__ abf) {
    int lane = threadIdx.x & 63;
    int v = blockIdx.x * 4 + (threadIdx.x >> 6);
    if (v >= N_NODES) return;
    int r0 = rowptr[v], r1 = rowptr[v + 1];
    int q = lane >> 4, li = lane & 15;
    float a0[8], a1[8];
    #pragma unroll
    for (int j = 0; j < 8; ++j) { a0[j] = 0.f; a1[j] = 0.f; }
    int e = r0 + q;
    for (; e + 4 < r1; e += 8) {
        int s0 = csr_src[e];
        int s1 = csr_src[e + 4];
        u16x8 u0 = *(const u16x8*)(abf + (size_t)s0 * 256 + 128 + li * 8);
        u16x8 u1 = *(const u16x8*)(abf + (size_t)s1 * 256 + 128 + li * 8);
        #pragma unroll
        for (int j = 0; j < 8; ++j) { a0[j] += b2f(u0[j]); a1[j] += b2f(u1[j]); }
    }
    if (e < r1) {
        int s0 = csr_src[e];
        u16x8 u0 = *(const u16x8*)(abf + (size_t)s0 * 256 + 128 + li * 8);
        #pragma unroll
        for (int j = 0; j < 8; ++j) a0[j] += b2f(u0[j]);
    }
    #pragma unroll
    for (int j = 0; j < 8; ++j) {
        float s = a0[j] + a1[j];
        s += __shfl_xor(s, 16);
        s += __shfl_xor(s, 32);
        a0[j] = s;
    }
    if (q == 0) {
        float id = inv_deg[v];
        u16x8 o;
        #pragma unroll
        for (int j = 0; j < 8; ++j) o[j] = f2b(a0[j] * id);
        *(u16x8*)(abf + (size_t)v * 256 + li * 8) = o;
    }
}

// K5: persistent MFMA GEMM, 32-row paired tasks (B-frag read once feeds two
// row-groups). 256 threads (256-VGPR budget) + sched_barrier fences keep the
// ~215-reg live set spill-free (r8/r9/r13 verified).
__global__ __launch_bounds__(256, 1) void k_mfma(
    const ushort* __restrict__ abf, const ushort* __restrict__ wbf,
    const float* __restrict__ b1, const float* __restrict__ w2t,
    float* __restrict__ zb, float* __restrict__ rb)
{
    __shared__ ushort bufB[16 * 8 * 512];   // 128KB: sub-buffer (n*8+kc) x 1KB

    int t = threadIdx.x;
    int w = t >> 6, l = t & 63;
    int lr = l & 15, lk = l >> 4;

    // stage all of B: wave w stages sub-buffers w*32 .. w*32+31
    #pragma unroll
    for (int j = 0; j < 32; ++j) {
        int sb = w * 32 + j;
        int n = sb >> 3, kc = sb & 7;
        gload16(wbf + (size_t)(n * 16 + lr) * 256 + kc * 32 + lk * 8,
                &bufB[sb * 512]);
    }
    __syncthreads();   // only barrier in the kernel

    int wid = blockIdx.x * 4 + w;                          // [0, 1024)
    int ps = (int)(((unsigned)wid * NPAIRS) >> 10);        // balanced /1024
    int pe = (int)(((unsigned)(wid + 1) * NPAIRS) >> 10);

    for (int p = ps; p < pe; ++p) {
        size_t r0 = (size_t)p * 32;
        short8v af0[8], af1[8];
        const ushort* pa0 = abf + (r0 + lr) * 256 + lk * 8;
        const ushort* pa1 = abf + (r0 + 16 + lr) * 256 + lk * 8;
        #pragma unroll
        for (int kc = 0; kc < 8; ++kc) {
            af0[kc] = *(const short8v*)(pa0 + kc * 32);
            af1[kc] = *(const short8v*)(pa1 + kc * 32);
        }
        __builtin_amdgcn_sched_barrier(0);

        f32x4 acc0[16] = {}, acc1[16] = {};
        #pragma unroll
        for (int kc = 0; kc < 8; ++kc) {
            #pragma unroll
            for (int n = 0; n < 8; ++n) {
                short8v bf = *(const short8v*)&bufB[(n * 8 + kc) * 512 + l * 8];
                acc0[n] = __builtin_amdgcn_mfma_f32_16x16x32_bf16(af0[kc], bf, acc0[n], 0, 0, 0);
                acc1[n] = __builtin_amdgcn_mfma_f32_16x16x32_bf16(af1[kc], bf, acc1[n], 0, 0, 0);
            }
            __builtin_amdgcn_sched_barrier(0);
            #pragma unroll
            for (int n = 8; n < 16; ++n) {
                short8v bf = *(const short8v*)&bufB[(n * 8 + kc) * 512 + l * 8];
                acc0[n] = __builtin_amdgcn_mfma_f32_16x16x32_bf16(af0[kc], bf, acc0[n], 0, 0, 0);
                acc1[n] = __builtin_amdgcn_mfma_f32_16x16x32_bf16(af1[kc], bf, acc1[n], 0, 0, 0);
            }
            __builtin_amdgcn_sched_barrier(0);
        }

        // epilogue per row-group: bias+relu, layer-2 partials, DPP reduce.
        #pragma unroll
        for (int g = 0; g < 2; ++g) {
            float pz[4][8];
            #pragma unroll
            for (int q = 0; q < 4; ++q)
                #pragma unroll
                for (int c = 0; c < 8; ++c) pz[q][c] = 0.f;
            #pragma unroll
            for (int n = 0; n < 16; ++n) {
                int col = n * 16 + lr;
                float bias = b1[col];
                f32x4 wa = *(const f32x4*)(w2t + col * 8);
                f32x4 wb = *(const f32x4*)(w2t + col * 8 + 4);
                #pragma unroll
                for (int q = 0; q < 4; ++q) {
                    float aq = g ? acc1[n][q] : acc0[n][q];
                    float h = fmaxf(aq + bias, 0.f);
                    pz[q][0] += h * wa[0]; pz[q][1] += h * wa[1];
                    pz[q][2] += h * wa[2]; pz[q][3] += h * wa[3];
                    pz[q][4] += h * wb[0]; pz[q][5] += h * wb[1];
                    pz[q][6] += h * wb[2]; pz[q][7] += h * wb[3];
                }
            }
            __builtin_amdgcn_sched_barrier(0);
            #pragma unroll
            for (int q = 0; q < 4; ++q)
                #pragma unroll
                for (int c = 0; c < 8; ++c)
                    pz[q][c] = row16_sum(pz[q][c]);
            if (lr == 0) {
                #pragma unroll
                for (int q = 0; q < 4; ++q) {
                    size_t row = r0 + g * 16 + lk * 4 + q;  // C/D row=(l>>4)*4+reg
                    if (row < N_NODES) {
                        *(float4*)(zb + row * 4) = make_float4(pz[q][0], pz[q][1], pz[q][2], pz[q][3]);
                        *(float4*)(rb + row * 4) = make_float4(pz[q][4], pz[q][5], pz[q][6], pz[q][7]);
                    }
                }
            }
        }
    }
}

// K6: aggregate z over in-edges, add bias + root term, log_softmax, write out.
// 16 LANES PER NODE (4 nodes/wave): avg degree is 16, so the old
// one-wave-per-node layout idled lanes 16-63 in the gather loop.
__global__ void k_final(const float* __restrict__ zb, const float* __restrict__ rb,
                        const int* __restrict__ rowptr, const int* __restrict__ csr_src,
                        const float* __restrict__ inv_deg, const float* __restrict__ b2,
                        float* __restrict__ out) {
    int t = threadIdx.x;
    int li = t & 15;
    int v = blockIdx.x * 16 + (t >> 4);
    if (v >= N_NODES) return;
    int r0 = rowptr[v], r1 = rowptr[v + 1];
    float a0 = 0.f, a1 = 0.f, a2 = 0.f, a3 = 0.f;
    for (int idx = r0 + li; idx < r1; idx += 16) {
        int s = csr_src[idx];
        float4 zv = *(const float4*)(zb + (size_t)s * 4);
        a0 += zv.x; a1 += zv.y; a2 += zv.z; a3 += zv.w;
    }
    #pragma unroll
    for (int off = 1; off < 16; off <<= 1) {
        a0 += __shfl_xor(a0, off);
        a1 += __shfl_xor(a1, off);
        a2 += __shfl_xor(a2, off);
        a3 += __shfl_xor(a3, off);
    }
    if (li == 0) {
        float id = inv_deg[v];
        float4 rv = *(const float4*)(rb + (size_t)v * 4);
        float4 b2v = *(const float4*)b2;
        float h0 = a0 * id + b2v.x + rv.x;
        float h1 = a1 * id + b2v.y + rv.y;
        float h2 = a2 * id + b2v.z + rv.z;
        float h3 = a3 * id + b2v.w + rv.w;
        float mx = fmaxf(fmaxf(h0, h1), fmaxf(h2, h3));
        float s = expf(h0 - mx) + expf(h1 - mx) + expf(h2 - mx) + expf(h3 - mx);
        float lse = mx + logf(s);
        *(float4*)(out + (size_t)v * 4) = make_float4(h0 - lse, h1 - lse, h2 - lse, h3 - lse);
    }
}

// ---------------------------------------------------------------------------
extern "C" void kernel_launch(void* const* d_in, const int* in_sizes, int n_in,
                              void* d_out, int out_size, void* d_ws, size_t ws_size,
                              hipStream_t stream) {
    const float* x   = (const float*)d_in[0];
    const int*   ei  = (const int*)d_in[1];
    const float* w1l = (const float*)d_in[2];
    const float* w1r = (const float*)d_in[3];
    const float* b1  = (const float*)d_in[4];
    const float* w2l = (const float*)d_in[5];
    const float* w2r = (const float*)d_in[6];
    const float* b2  = (const float*)d_in[7];
    float* out = (float*)d_out;

    char* ws = (char*)d_ws;
    size_t off = 0;
    auto alloc = [&](size_t bytes) -> void* {
        void* p = ws + off;
        off = (off + bytes + 255) & ~(size_t)255;
        return p;
    };
    int* bcur    = (int*)alloc(512 * 4);
    int* rowptr  = (int*)alloc((N_NODES + 1) * 4);
    int* csr_src = (int*)alloc((size_t)N_EDGES * 4);
    int* ebuf    = (int*)alloc((size_t)NB * SLACK * 4);           // 12.8 MB slack
    float* inv_deg = (float*)alloc(N_NODES * 4);
    ushort* abf  = (ushort*)alloc((size_t)N_ROWS_PAD * 256 * 2);  // [agg | x] bf16
    ushort* wbf  = (ushort*)alloc((size_t)256 * 256 * 2);         // [w1l | w1r] bf16
    float* w2t   = (float*)alloc(256 * 8 * 4);                    // [col][z0..3 r0..3]
    float* zb    = (float*)alloc((size_t)N_NODES * 4 * 4);
    float* rb    = (float*)alloc((size_t)N_NODES * 4 * 4);

    hipMemsetAsync(bcur, 0, 512 * 4, stream);
    k_front<<<BKB + XCB + 256, 256, 0, stream>>>(ei, bcur, ebuf, x, abf,
                                                 w1l, w1r, w2l, w2r, wbf, w2t);
    k_place<<<NB, 256, 0, stream>>>(bcur, ebuf, rowptr, inv_deg, csr_src);
    k_aggregate<<<(N_NODES + 3) / 4, 256, 0, stream>>>(rowptr, csr_src, inv_deg, abf);
    k_mfma<<<GEMM_BLOCKS, 256, 0, stream>>>(abf, wbf, b1, w2t, zb, rb);
    k_final<<<(N_NODES + 15) / 16, 256, 0, stream>>>(zb, rb, rowptr, csr_src, inv_deg, b2, out);
}